// Round 2
// baseline (985.899 us; speedup 1.0000x reference)
//
#include <hip/hip_runtime.h>

typedef __attribute__((ext_vector_type(8))) _Float16 half8;
typedef __attribute__((ext_vector_type(4))) _Float16 half4;
typedef __attribute__((ext_vector_type(4))) float floatx4;

#define DI __device__ __forceinline__

DI void gl_lds16(const void* g, void* l) {
    __builtin_amdgcn_global_load_lds(
        (__attribute__((address_space(1))) void*)(g),
        (__attribute__((address_space(3))) void*)(l), 16, 0, 0);
}

// ------------- weight split: (CO, CI, 27) fp32 -> (CO, 27, CI) f16 hi/lo, x64 scale -------------
__global__ void wt_split(const float* __restrict__ win, _Float16* __restrict__ wh,
                         _Float16* __restrict__ wl, int CI) {
    const int co = blockIdx.x;
    const int K = CI * 27;
    const float* src = win + (size_t)co * K;
    _Float16* dh = wh + (size_t)co * K;
    _Float16* dl = wl + (size_t)co * K;
    for (int idx = threadIdx.x; idx < K; idx += blockDim.x) {
        const int ci = idx / 27;
        const int tap = idx - ci * 27;
        const float x = src[idx] * 64.0f;          // scale lo-parts out of fp16 subnormals
        const _Float16 h = (_Float16)x;
        dh[tap * CI + ci] = h;
        dl[tap * CI + ci] = (_Float16)(x - (float)h);
    }
}

// ------------- input split+transpose: (256, 65536) fp32 -> (65536, 256) f16 hi/lo -------------
__global__ void in_split(const float* __restrict__ in, _Float16* __restrict__ oh,
                         _Float16* __restrict__ ol) {
    const int lane = threadIdx.x;                  // 64
    const int ci = blockIdx.x * 64 + lane;         // 0..255
    const int s0 = blockIdx.y * 32;                // 0..65535
    const float* src = in + (size_t)ci * 65536 + s0;
    float v[32];
#pragma unroll
    for (int q = 0; q < 8; ++q) *(float4*)(v + q * 4) = *(const float4*)(src + q * 4);
    const int cdst = blockIdx.x * 64 + lane;
#pragma unroll
    for (int j = 0; j < 32; ++j) {
        const _Float16 h = (_Float16)v[j];
        oh[(size_t)(s0 + j) * 256 + cdst] = h;
        ol[(size_t)(s0 + j) * 256 + cdst] = (_Float16)(v[j] - (float)h);
    }
}

// ------------- conv1: M=co(512), N=(t,h,w), K=27*256, 3-pass hi/lo MFMA -------------
__global__ __launch_bounds__(256, 2) void conv1_mfma(
        const _Float16* __restrict__ xh, const _Float16* __restrict__ xl,
        const _Float16* __restrict__ wh, const _Float16* __restrict__ wl,
        const float* __restrict__ b1,
        _Float16* __restrict__ yh, _Float16* __restrict__ yl) {
    __shared__ __align__(16) _Float16 Ah[128 * 32];
    __shared__ __align__(16) _Float16 Al[128 * 32];
    __shared__ __align__(16) _Float16 Bh[128 * 32];
    __shared__ __align__(16) _Float16 Bl[128 * 32];
    const int tid = threadIdx.x;
    const int co_blk = blockIdx.x;      // 0..3
    const int t = blockIdx.y;           // 0..63
    const int h0 = blockIdx.z * 8;      // 0 or 8
    const int wid = tid >> 6, lane = tid & 63;
    const int wm = wid & 1, wn = wid >> 1;
    const int sr = tid >> 2, sch = tid & 3;
    const int qk = (lane >> 4) * 8, ml = lane & 15;

    floatx4 zz = {0.f, 0.f, 0.f, 0.f};
    floatx4 acc[4][4];
#pragma unroll
    for (int i = 0; i < 4; ++i)
#pragma unroll
        for (int j = 0; j < 4; ++j) acc[i][j] = zz;

    const size_t wbo = (size_t)co_blk * 128 * 6912;

    for (int kc = 0; kc < 216; ++kc) {
        const int tap = kc >> 3;
        const int ci0 = (kc & 7) << 5;
        const int kt = tap / 9;
        const int r9 = tap - kt * 9;
        const int kh = r9 / 3;
        const int kw = r9 - kh * 3;
        const int it = t + kt - 1;
        __syncthreads();
        {   // A tiles (hi & lo): 128 co x 32 k, async global->LDS, lane-contiguous
            const size_t g = wbo + (size_t)sr * 6912 + tap * 256 + ci0 + sch * 8;
            gl_lds16(wh + g, &Ah[tid * 8]);
            gl_lds16(wh + g + (size_t)64 * 6912, &Ah[2048 + tid * 8]);
            gl_lds16(wl + g, &Al[tid * 8]);
            gl_lds16(wl + g + (size_t)64 * 6912, &Al[2048 + tid * 8]);
        }
        {   // B tiles: 128 n x 32 k im2col gather with zero pad
            const bool tok = ((unsigned)it < 64u);
#pragma unroll
            for (int rb = 0; rb < 2; ++rb) {
                const int n = sr + rb * 64;
                const int h = h0 + (n >> 4), w = n & 15;
                const int ih = 2 * h + kh - 1, iw = 2 * w + kw - 1;
                uint4 vh = make_uint4(0u, 0u, 0u, 0u);
                uint4 vl = make_uint4(0u, 0u, 0u, 0u);
                if (tok && ((unsigned)ih < 32u) && ((unsigned)iw < 32u)) {
                    const size_t off = (((size_t)it * 32 + ih) * 32 + iw) * 256 + ci0 + sch * 8;
                    vh = *(const uint4*)(xh + off);
                    vl = *(const uint4*)(xl + off);
                }
                *(uint4*)&Bh[n * 32 + sch * 8] = vh;
                *(uint4*)&Bl[n * 32 + sch * 8] = vl;
            }
        }
        __syncthreads();
        half8 ah[4], alo[4], bh[4], blo[4];
#pragma unroll
        for (int mi = 0; mi < 4; ++mi) {
            ah[mi]  = *(const half8*)&Ah[(wm * 64 + mi * 16 + ml) * 32 + qk];
            alo[mi] = *(const half8*)&Al[(wm * 64 + mi * 16 + ml) * 32 + qk];
        }
#pragma unroll
        for (int ni = 0; ni < 4; ++ni) {
            bh[ni]  = *(const half8*)&Bh[(wn * 64 + ni * 16 + ml) * 32 + qk];
            blo[ni] = *(const half8*)&Bl[(wn * 64 + ni * 16 + ml) * 32 + qk];
        }
#pragma unroll
        for (int mi = 0; mi < 4; ++mi)
#pragma unroll
            for (int ni = 0; ni < 4; ++ni) {
                acc[mi][ni] = __builtin_amdgcn_mfma_f32_16x16x32_f16(ah[mi],  bh[ni],  acc[mi][ni], 0, 0, 0);
                acc[mi][ni] = __builtin_amdgcn_mfma_f32_16x16x32_f16(ah[mi],  blo[ni], acc[mi][ni], 0, 0, 0);
                acc[mi][ni] = __builtin_amdgcn_mfma_f32_16x16x32_f16(alo[mi], bh[ni],  acc[mi][ni], 0, 0, 0);
            }
    }

    // epilogue: unscale, +bias, split fp32 value into f16 hi/lo, store channel-last
    const int qr = (lane >> 4) * 4;
#pragma unroll
    for (int mi = 0; mi < 4; ++mi) {
        const int co = co_blk * 128 + wm * 64 + mi * 16 + qr;
#pragma unroll
        for (int ni = 0; ni < 4; ++ni) {
            const int n = wn * 64 + ni * 16 + ml;
            const int h = h0 + (n >> 4), w = n & 15;
            const size_t base = (((size_t)t * 16 + h) * 16 + w) * 512 + co;
            half4 hv, lv;
#pragma unroll
            for (int r = 0; r < 4; ++r) {
                const float v = acc[mi][ni][r] * 0.015625f + b1[co + r];
                const _Float16 hb = (_Float16)v;
                hv[r] = hb;
                lv[r] = (_Float16)(v - (float)hb);
            }
            *(half4*)(yh + base) = hv;
            *(half4*)(yl + base) = lv;
        }
    }
}

// ------------- conv2: M=co2(512), N=64 (8x8 per t), K=27*512, K-split 2, 3-pass -------------
__global__ __launch_bounds__(256, 2) void conv2_mfma(
        const _Float16* __restrict__ xh, const _Float16* __restrict__ xl,
        const _Float16* __restrict__ wh, const _Float16* __restrict__ wl,
        float* __restrict__ x2p) {
    __shared__ __align__(16) _Float16 Ah[128 * 32];
    __shared__ __align__(16) _Float16 Al[128 * 32];
    __shared__ __align__(16) _Float16 Bh[64 * 32];
    __shared__ __align__(16) _Float16 Bl[64 * 32];
    const int tid = threadIdx.x;
    const int co_blk = blockIdx.x;      // 0..3
    const int t = blockIdx.y;           // 0..63
    const int ks = blockIdx.z;          // 0..1
    const int wid = tid >> 6, lane = tid & 63;
    const int wm = wid & 1, wn = wid >> 1;
    const int sr = tid >> 2, sch = tid & 3;
    const int qk = (lane >> 4) * 8, ml = lane & 15;

    floatx4 zz = {0.f, 0.f, 0.f, 0.f};
    floatx4 acc[4][2];
#pragma unroll
    for (int i = 0; i < 4; ++i) { acc[i][0] = zz; acc[i][1] = zz; }

    const size_t wbo = (size_t)co_blk * 128 * 13824;

    for (int i = 0; i < 216; ++i) {
        const int kc = ks * 216 + i;
        const int tap = kc >> 4;
        const int ci0 = (kc & 15) << 5;
        const int kt = tap / 9;
        const int r9 = tap - kt * 9;
        const int kh = r9 / 3;
        const int kw = r9 - kh * 3;
        const int it = t + kt - 1;
        __syncthreads();
        {
            const size_t g = wbo + (size_t)sr * 13824 + tap * 512 + ci0 + sch * 8;
            gl_lds16(wh + g, &Ah[tid * 8]);
            gl_lds16(wh + g + (size_t)64 * 13824, &Ah[2048 + tid * 8]);
            gl_lds16(wl + g, &Al[tid * 8]);
            gl_lds16(wl + g + (size_t)64 * 13824, &Al[2048 + tid * 8]);
        }
        {
            const int h = sr >> 3, w = sr & 7;
            const int ih = 2 * h + kh - 1, iw = 2 * w + kw - 1;
            uint4 vh = make_uint4(0u, 0u, 0u, 0u);
            uint4 vl = make_uint4(0u, 0u, 0u, 0u);
            if (((unsigned)it < 64u) && ((unsigned)ih < 16u) && ((unsigned)iw < 16u)) {
                const size_t off = (((size_t)it * 16 + ih) * 16 + iw) * 512 + ci0 + sch * 8;
                vh = *(const uint4*)(xh + off);
                vl = *(const uint4*)(xl + off);
            }
            *(uint4*)&Bh[sr * 32 + sch * 8] = vh;
            *(uint4*)&Bl[sr * 32 + sch * 8] = vl;
        }
        __syncthreads();
        half8 ah[4], alo[4], bh[2], blo[2];
#pragma unroll
        for (int mi = 0; mi < 4; ++mi) {
            ah[mi]  = *(const half8*)&Ah[(wm * 64 + mi * 16 + ml) * 32 + qk];
            alo[mi] = *(const half8*)&Al[(wm * 64 + mi * 16 + ml) * 32 + qk];
        }
#pragma unroll
        for (int ni = 0; ni < 2; ++ni) {
            bh[ni]  = *(const half8*)&Bh[(wn * 32 + ni * 16 + ml) * 32 + qk];
            blo[ni] = *(const half8*)&Bl[(wn * 32 + ni * 16 + ml) * 32 + qk];
        }
#pragma unroll
        for (int mi = 0; mi < 4; ++mi)
#pragma unroll
            for (int ni = 0; ni < 2; ++ni) {
                acc[mi][ni] = __builtin_amdgcn_mfma_f32_16x16x32_f16(ah[mi],  bh[ni],  acc[mi][ni], 0, 0, 0);
                acc[mi][ni] = __builtin_amdgcn_mfma_f32_16x16x32_f16(ah[mi],  blo[ni], acc[mi][ni], 0, 0, 0);
                acc[mi][ni] = __builtin_amdgcn_mfma_f32_16x16x32_f16(alo[mi], bh[ni],  acc[mi][ni], 0, 0, 0);
            }
    }

    const int qr = (lane >> 4) * 4;
#pragma unroll
    for (int mi = 0; mi < 4; ++mi)
#pragma unroll
        for (int ni = 0; ni < 2; ++ni) {
            const int n = wn * 32 + ni * 16 + ml;
#pragma unroll
            for (int r = 0; r < 4; ++r) {
                const int co = co_blk * 128 + wm * 64 + mi * 16 + qr + r;
                x2p[(((size_t)ks * 512 + co) * 64 + t) * 64 + n] = acc[mi][ni][r];
            }
        }
}

// ------------- feat: sum K-split partials, unscale, max over 64 spatial, +bias -------------
__global__ void feat_reduce(const float* __restrict__ x2p,
                            const float* __restrict__ b2,
                            float* __restrict__ feat) {
    const int idx = blockIdx.x * 256 + threadIdx.x;   // 32768 = 512*64
    const int c = idx >> 6, t = idx & 63;
    const float* p0 = x2p + ((size_t)c * 64 + t) * 64;
    const float* p1 = p0 + (size_t)512 * 64 * 64;
    float mx = -3.4e38f;
#pragma unroll 8
    for (int n = 0; n < 64; ++n) mx = fmaxf(mx, p0[n] + p1[n]);
    feat[(size_t)t * 512 + c] = mx * 0.015625f + b2[c];
}

// ------------- head: scores/deltas (32 x 64) = W(32x512) @ feat^T (fp32) -------------
__global__ void head_kernel(const float* __restrict__ feat,
                            const float* __restrict__ sw,
                            const float* __restrict__ sb,
                            const float* __restrict__ dw,
                            const float* __restrict__ db,
                            float* __restrict__ scoreL,
                            float* __restrict__ deltaL) {
    __shared__ float fr[512];
    __shared__ float partial[32][8];
    const int t = blockIdx.x, tid = threadIdx.x;
    fr[tid] = feat[(size_t)t * 512 + tid];
    fr[tid + 256] = feat[(size_t)t * 512 + 256 + tid];
    __syncthreads();
    const int o = tid & 31, part = tid >> 5;
    const float* wrow = (o < 16) ? (sw + (size_t)o * 512) : (dw + (size_t)(o - 16) * 512);
    float s = 0.f;
    const int j0 = part * 64;
#pragma unroll 16
    for (int j = 0; j < 64; ++j) s += wrow[j0 + j] * fr[j0 + j];
    partial[o][part] = s;
    __syncthreads();
    if (tid < 32) {
        float tot = 0.f;
#pragma unroll
        for (int p = 0; p < 8; ++p) tot += partial[tid][p];
        tot += (tid < 16) ? sb[tid] : db[tid - 16];
        if (tid < 16) scoreL[tid * 64 + t] = tot;
        else deltaL[(tid - 16) * 64 + t] = tot;
    }
}

// ------------- NMS + labels + losses (single block), fp32 output -------------
__global__ void nms_loss_kernel(const float* __restrict__ scoreL,
                                const float* __restrict__ deltaL,
                                const float* __restrict__ gt,
                                const int* __restrict__ video_len,
                                float* __restrict__ out) {
    __shared__ float bs[512], be[512], fgv[512], lp0s[512], lp1s[512], dcs[512], dls[512];
    __shared__ float gs[8], ge[8];
    __shared__ int lab[512], argg[512];
    __shared__ float redv[4];
    __shared__ int redi[4];
    __shared__ float brd[2];
    __shared__ float rsum[4][4];

    const int tid = threadIdx.x;
    if (tid < 8) { gs[tid] = gt[2 * tid]; ge[tid] = gt[2 * tid + 1]; }

    for (int n = tid; n < 512; n += 256) {
        const int a = n >> 6, tt = n & 63;
        const float s0 = scoreL[a * 64 + tt], s1 = scoreL[(8 + a) * 64 + tt];
        const float mm = fmaxf(s0, s1);
        const float lse = mm + logf(expf(s0 - mm) + expf(s1 - mm));
        const float l0 = s0 - lse, l1 = s1 - lse;
        const float dc = deltaL[a * 64 + tt], dl = deltaL[(8 + a) * 64 + tt];
        const float alen = 8.0f * (float)(1 << a);
        const float center = ((float)tt + 0.5f) * 8.0f;
        const float pc = center + dc * alen;
        const float dlc = fminf(fmaxf(dl, -10.0f), 10.0f);
        const float pl = alen * expf(dlc);
        float ps = pc - pl * 0.5f; ps = fminf(fmaxf(ps, 0.0f), 512.0f);
        float pe = pc + pl * 0.5f; pe = fminf(fmaxf(pe, 0.0f), 512.0f);
        bs[n] = ps; be[n] = pe;
        fgv[n] = ((pe - ps) >= 4.0f) ? expf(l1) : -1e9f;
        lp0s[n] = l0; lp1s[n] = l1; dcs[n] = dc; dls[n] = dl;
    }
    __syncthreads();

    for (int itn = 0; itn < 100; ++itn) {
        float v = fgv[tid]; int idx = tid;
        { const float v2 = fgv[tid + 256]; if (v2 > v) { v = v2; idx = tid + 256; } }
#pragma unroll
        for (int off = 32; off > 0; off >>= 1) {
            const float ov = __shfl_down(v, off);
            const int oi = __shfl_down(idx, off);
            if (ov > v || (ov == v && oi < idx)) { v = ov; idx = oi; }
        }
        if ((tid & 63) == 0) { redv[tid >> 6] = v; redi[tid >> 6] = idx; }
        __syncthreads();
        if (tid == 0) {
            float bv = redv[0]; int bi = redi[0];
            for (int w2 = 1; w2 < 4; ++w2) {
                if (redv[w2] > bv || (redv[w2] == bv && redi[w2] < bi)) { bv = redv[w2]; bi = redi[w2]; }
            }
            brd[0] = bv; brd[1] = __int_as_float(bi);
            const bool kept = bv > -5e8f;
            out[2 * itn] = kept ? bs[bi] : 0.0f;
            out[2 * itn + 1] = kept ? be[bi] : 0.0f;
            out[200 + itn] = kept ? bv : 0.0f;
        }
        __syncthreads();
        const int bi = __float_as_int(brd[1]);
        const float b0 = bs[bi], b1v = be[bi];
#pragma unroll
        for (int rr = 0; rr < 2; ++rr) {
            const int n = tid + rr * 256;
            const float inter = fmaxf(fminf(b1v, be[n]) - fmaxf(b0, bs[n]), 0.0f);
            const float uni = (b1v - b0) + (be[n] - bs[n]) - inter;
            const float iou = inter / fmaxf(uni, 1e-6f);
            if (iou > 0.7f || n == bi) fgv[n] = -1e9f;
        }
        __syncthreads();
    }

    // anchor labels vs GT
    for (int n = tid; n < 512; n += 256) {
        const int a = n >> 6, tt = n & 63;
        const float alen = 8.0f * (float)(1 << a);
        const float center = ((float)tt + 0.5f) * 8.0f;
        const float as_ = center - alen * 0.5f, ae_ = center + alen * 0.5f;
        float mx = -1.0f; int ag = 0;
        for (int g = 0; g < 8; ++g) {
            const float inter = fmaxf(fminf(ae_, ge[g]) - fmaxf(as_, gs[g]), 0.0f);
            const float uni = (ae_ - as_) + (ge[g] - gs[g]) - inter;
            const float iou = inter / fmaxf(uni, 1e-6f);
            if (iou > mx) { mx = iou; ag = g; }
        }
        int l = (mx < 0.3f) ? 0 : -1;
        if (mx >= 0.7f) l = 1;
        lab[n] = l; argg[n] = ag;
    }
    __syncthreads();

    // best anchor per GT -> force label 1 (first-max tie like jnp.argmax)
    for (int g = 0; g < 8; ++g) {
        float v = -1.0f; int idx = 0;
#pragma unroll
        for (int rr = 0; rr < 2; ++rr) {
            const int n = tid + rr * 256;
            const int a = n >> 6, tt = n & 63;
            const float alen = 8.0f * (float)(1 << a);
            const float center = ((float)tt + 0.5f) * 8.0f;
            const float as_ = center - alen * 0.5f, ae_ = center + alen * 0.5f;
            const float inter = fmaxf(fminf(ae_, ge[g]) - fmaxf(as_, gs[g]), 0.0f);
            const float uni = (ae_ - as_) + (ge[g] - gs[g]) - inter;
            const float iou = inter / fmaxf(uni, 1e-6f);
            if (iou > v || (iou == v && n < idx)) { v = iou; idx = n; }
        }
#pragma unroll
        for (int off = 32; off > 0; off >>= 1) {
            const float ov = __shfl_down(v, off);
            const int oi = __shfl_down(idx, off);
            if (ov > v || (ov == v && oi < idx)) { v = ov; idx = oi; }
        }
        if ((tid & 63) == 0) { redv[tid >> 6] = v; redi[tid >> 6] = idx; }
        __syncthreads();
        if (tid == 0) {
            float bv = redv[0]; int bi = redi[0];
            for (int w2 = 1; w2 < 4; ++w2) {
                if (redv[w2] > bv || (redv[w2] == bv && redi[w2] < bi)) { bv = redv[w2]; bi = redi[w2]; }
            }
            lab[bi] = 1;
        }
        __syncthreads();
    }

    // losses
    float nll_s = 0.f, msk_s = 0.f, reg_s = 0.f, pos_s = 0.f;
    const float vl = (float)video_len[0];
    for (int n = tid; n < 512; n += 256) {
        const int a = n >> 6, tt = n & 63;
        const float alen = 8.0f * (float)(1 << a);
        const float center = ((float)tt + 0.5f) * 8.0f;
        const float as_ = center - alen * 0.5f, ae_ = center + alen * 0.5f;
        int l = lab[n];
        if (!((as_ >= 0.0f) && (ae_ <= vl))) l = -1;
        if (l >= 0) {
            msk_s += 1.0f;
            nll_s -= (l == 1) ? lp1s[n] : lp0s[n];
            if (l == 1) {
                pos_s += 1.0f;
                const int g = argg[n];
                const float gc = (gs[g] + ge[g]) * 0.5f;
                const float gl = fmaxf(ge[g] - gs[g], 1e-6f);
                const float r0 = (gc - center) / alen;
                const float r1 = logf(gl / alen);
                const float d0 = dcs[n] - r0, d1 = dls[n] - r1;
                float s = (fabsf(d0) < 1.0f) ? (0.5f * d0 * d0) : (fabsf(d0) - 0.5f);
                s += (fabsf(d1) < 1.0f) ? (0.5f * d1 * d1) : (fabsf(d1) - 0.5f);
                reg_s += s;
            }
        }
    }
    float sums[4] = {nll_s, msk_s, reg_s, pos_s};
#pragma unroll
    for (int j = 0; j < 4; ++j) {
        float v = sums[j];
#pragma unroll
        for (int off = 32; off > 0; off >>= 1) v += __shfl_down(v, off);
        if ((tid & 63) == 0) rsum[tid >> 6][j] = v;
    }
    __syncthreads();
    if (tid == 0) {
        float tot[4];
#pragma unroll
        for (int j = 0; j < 4; ++j) tot[j] = rsum[0][j] + rsum[1][j] + rsum[2][j] + rsum[3][j];
        out[300] = tot[0] / fmaxf(tot[1], 1.0f);
        out[301] = tot[2] / fmaxf(tot[3], 1.0f);
    }
}

extern "C" void kernel_launch(void* const* d_in, const int* in_sizes, int n_in,
                              void* d_out, int out_size, void* d_ws, size_t ws_size,
                              hipStream_t stream) {
    const float* base_feat = (const float*)d_in[0];
    const float* gt        = (const float*)d_in[1];
    const int*   video_len = (const int*)d_in[2];
    const float* w1        = (const float*)d_in[3];
    const float* b1        = (const float*)d_in[4];
    const float* w2        = (const float*)d_in[5];
    const float* b2        = (const float*)d_in[6];
    const float* sw        = (const float*)d_in[7];
    const float* sb        = (const float*)d_in[8];
    const float* dw        = (const float*)d_in[9];
    const float* db        = (const float*)d_in[10];

    char* ws = (char*)d_ws;
    _Float16* w1h = (_Float16*)ws;  ws += (size_t)512 * 6912 * 2;       // 7,077,888
    _Float16* w1l = (_Float16*)ws;  ws += (size_t)512 * 6912 * 2;
    _Float16* w2h = (_Float16*)ws;  ws += (size_t)512 * 13824 * 2;      // 14,155,776
    _Float16* w2l = (_Float16*)ws;  ws += (size_t)512 * 13824 * 2;
    _Float16* inh = (_Float16*)ws;  ws += (size_t)65536 * 256 * 2;      // 33,554,432
    _Float16* inl = (_Float16*)ws;  ws += (size_t)65536 * 256 * 2;
    _Float16* x1h = (_Float16*)ws;  ws += (size_t)64 * 16 * 16 * 512 * 2;
    _Float16* x1l = (_Float16*)ws;  ws += (size_t)64 * 16 * 16 * 512 * 2;
    float* feat   = (float*)ws;     ws += (size_t)64 * 512 * 4;
    float* scoreL = (float*)ws;     ws += (size_t)16 * 64 * 4;
    float* deltaL = (float*)ws;     ws += (size_t)16 * 64 * 4;
    // x2p (2,512,64,64) fp32 = 16.8 MB reuses the inh region (consumed by conv1)
    float* x2p = (float*)inh;

    wt_split<<<512, 256, 0, stream>>>(w1, w1h, w1l, 256);
    wt_split<<<512, 256, 0, stream>>>(w2, w2h, w2l, 512);
    in_split<<<dim3(4, 2048), 64, 0, stream>>>(base_feat, inh, inl);
    conv1_mfma<<<dim3(4, 64, 2), 256, 0, stream>>>(inh, inl, w1h, w1l, b1, x1h, x1l);
    conv2_mfma<<<dim3(4, 64, 2), 256, 0, stream>>>(x1h, x1l, w2h, w2l, x2p);
    feat_reduce<<<128, 256, 0, stream>>>(x2p, b2, feat);
    head_kernel<<<64, 256, 0, stream>>>(feat, sw, sb, dw, db, scoreL, deltaL);
    nms_loss_kernel<<<1, 256, 0, stream>>>(scoreL, deltaL, gt, video_len,
                                           (float*)d_out);
}

// Round 3
// 960.961 us; speedup vs baseline: 1.0260x; 1.0260x over previous
//
#include <hip/hip_runtime.h>

typedef __attribute__((ext_vector_type(8))) _Float16 half8;
typedef __attribute__((ext_vector_type(4))) _Float16 half4;
typedef __attribute__((ext_vector_type(4))) float floatx4;

#define DI __device__ __forceinline__

DI void gl_lds16(const void* g, void* l) {
    __builtin_amdgcn_global_load_lds(
        (__attribute__((address_space(1))) void*)(g),
        (__attribute__((address_space(3))) void*)(l), 16, 0, 0);
}

// ------------- weight split: (CO, CI, 27) fp32 -> (CO, 27, CI) f16 hi/lo, x64 scale -------------
__global__ void wt_split(const float* __restrict__ win, _Float16* __restrict__ wh,
                         _Float16* __restrict__ wl, int CI) {
    const int co = blockIdx.x;
    const int K = CI * 27;
    const float* src = win + (size_t)co * K;
    _Float16* dh = wh + (size_t)co * K;
    _Float16* dl = wl + (size_t)co * K;
    for (int idx = threadIdx.x; idx < K; idx += blockDim.x) {
        const int ci = idx / 27;
        const int tap = idx - ci * 27;
        const float x = src[idx] * 64.0f;          // scale lo-parts out of fp16 subnormals
        const _Float16 h = (_Float16)x;
        dh[tap * CI + ci] = h;
        dl[tap * CI + ci] = (_Float16)(x - (float)h);
    }
}

// ------------- input split+transpose: (256, 65536) fp32 -> (65536, 256) f16 hi/lo -------------
__global__ void in_split(const float* __restrict__ in, _Float16* __restrict__ oh,
                         _Float16* __restrict__ ol) {
    const int lane = threadIdx.x;                  // 64
    const int ci = blockIdx.x * 64 + lane;         // 0..255
    const int s0 = blockIdx.y * 32;                // 0..65535
    const float* src = in + (size_t)ci * 65536 + s0;
    float v[32];
#pragma unroll
    for (int q = 0; q < 8; ++q) *(float4*)(v + q * 4) = *(const float4*)(src + q * 4);
    const int cdst = blockIdx.x * 64 + lane;
#pragma unroll
    for (int j = 0; j < 32; ++j) {
        const _Float16 h = (_Float16)v[j];
        oh[(size_t)(s0 + j) * 256 + cdst] = h;
        ol[(size_t)(s0 + j) * 256 + cdst] = (_Float16)(v[j] - (float)h);
    }
}

// ------------- conv1: M=co(512), N=(t,h,w), K=27*256, 3-pass hi/lo MFMA, swizzled LDS -------------
__global__ __launch_bounds__(256, 2) void conv1_mfma(
        const _Float16* __restrict__ xh, const _Float16* __restrict__ xl,
        const _Float16* __restrict__ wh, const _Float16* __restrict__ wl,
        const float* __restrict__ b1,
        _Float16* __restrict__ yh, _Float16* __restrict__ yl) {
    __shared__ __align__(16) _Float16 Ah[128 * 32];
    __shared__ __align__(16) _Float16 Al[128 * 32];
    __shared__ __align__(16) _Float16 Bh[128 * 32];
    __shared__ __align__(16) _Float16 Bl[128 * 32];
    const int tid = threadIdx.x;
    const int co_blk = blockIdx.x;      // 0..3
    const int t = blockIdx.y;           // 0..63
    const int h0 = blockIdx.z * 8;      // 0 or 8
    const int wid = tid >> 6, lane = tid & 63;
    const int wm = wid & 1, wn = wid >> 1;
    const int sr = tid >> 2, sch = tid & 3;
    const int ml = lane & 15;
    // LDS chunk swizzle: slot chunk c' = c ^ ((row>>1)&3); row bases are mult-of-16
    const int ssel = (sr >> 1) & 3;                      // staging-side selector
    const int sch2 = sch ^ ssel;                         // swizzled global chunk for A staging
    const int kq = (((lane >> 4) ^ ((ml >> 1) & 3))) * 8; // read-side swizzled chunk offset

    floatx4 zz = {0.f, 0.f, 0.f, 0.f};
    floatx4 acc[4][4];
#pragma unroll
    for (int i = 0; i < 4; ++i)
#pragma unroll
        for (int j = 0; j < 4; ++j) acc[i][j] = zz;

    const size_t wbo = (size_t)co_blk * 128 * 6912;

    for (int kc = 0; kc < 216; ++kc) {
        const int tap = kc >> 3;
        const int ci0 = (kc & 7) << 5;
        const int kt = tap / 9;
        const int r9 = tap - kt * 9;
        const int kh = r9 / 3;
        const int kw = r9 - kh * 3;
        const int it = t + kt - 1;
        __syncthreads();
        {   // A tiles (hi & lo): swizzled global chunk so LDS slot (lane*16B) gets c^sel data
            const size_t g = wbo + (size_t)sr * 6912 + tap * 256 + ci0 + sch2 * 8;
            gl_lds16(wh + g, &Ah[tid * 8]);
            gl_lds16(wh + g + (size_t)64 * 6912, &Ah[2048 + tid * 8]);
            gl_lds16(wl + g, &Al[tid * 8]);
            gl_lds16(wl + g + (size_t)64 * 6912, &Al[2048 + tid * 8]);
        }
        {   // B tiles: im2col gather, write to swizzled LDS slot
            const bool tok = ((unsigned)it < 64u);
#pragma unroll
            for (int rb = 0; rb < 2; ++rb) {
                const int n = sr + rb * 64;
                const int h = h0 + (n >> 4), w = n & 15;
                const int ih = 2 * h + kh - 1, iw = 2 * w + kw - 1;
                uint4 vh = make_uint4(0u, 0u, 0u, 0u);
                uint4 vl = make_uint4(0u, 0u, 0u, 0u);
                if (tok && ((unsigned)ih < 32u) && ((unsigned)iw < 32u)) {
                    const size_t off = (((size_t)it * 32 + ih) * 32 + iw) * 256 + ci0 + sch * 8;
                    vh = *(const uint4*)(xh + off);
                    vl = *(const uint4*)(xl + off);
                }
                *(uint4*)&Bh[n * 32 + sch2 * 8] = vh;
                *(uint4*)&Bl[n * 32 + sch2 * 8] = vl;
            }
        }
        __syncthreads();
        half8 ah[4], alo[4], bh[4], blo[4];
#pragma unroll
        for (int mi = 0; mi < 4; ++mi) {
            ah[mi]  = *(const half8*)&Ah[(wm * 64 + mi * 16 + ml) * 32 + kq];
            alo[mi] = *(const half8*)&Al[(wm * 64 + mi * 16 + ml) * 32 + kq];
        }
#pragma unroll
        for (int ni = 0; ni < 4; ++ni) {
            bh[ni]  = *(const half8*)&Bh[(wn * 64 + ni * 16 + ml) * 32 + kq];
            blo[ni] = *(const half8*)&Bl[(wn * 64 + ni * 16 + ml) * 32 + kq];
        }
#pragma unroll
        for (int mi = 0; mi < 4; ++mi)
#pragma unroll
            for (int ni = 0; ni < 4; ++ni) {
                acc[mi][ni] = __builtin_amdgcn_mfma_f32_16x16x32_f16(ah[mi],  bh[ni],  acc[mi][ni], 0, 0, 0);
                acc[mi][ni] = __builtin_amdgcn_mfma_f32_16x16x32_f16(ah[mi],  blo[ni], acc[mi][ni], 0, 0, 0);
                acc[mi][ni] = __builtin_amdgcn_mfma_f32_16x16x32_f16(alo[mi], bh[ni],  acc[mi][ni], 0, 0, 0);
            }
    }

    // epilogue: unscale, +bias, split fp32 value into f16 hi/lo, store channel-last
    const int qr = (lane >> 4) * 4;
#pragma unroll
    for (int mi = 0; mi < 4; ++mi) {
        const int co = co_blk * 128 + wm * 64 + mi * 16 + qr;
#pragma unroll
        for (int ni = 0; ni < 4; ++ni) {
            const int n = wn * 64 + ni * 16 + ml;
            const int h = h0 + (n >> 4), w = n & 15;
            const size_t base = (((size_t)t * 16 + h) * 16 + w) * 512 + co;
            half4 hv, lv;
#pragma unroll
            for (int r = 0; r < 4; ++r) {
                const float v = acc[mi][ni][r] * 0.015625f + b1[co + r];
                const _Float16 hb = (_Float16)v;
                hv[r] = hb;
                lv[r] = (_Float16)(v - (float)hb);
            }
            *(half4*)(yh + base) = hv;
            *(half4*)(yl + base) = lv;
        }
    }
}

// ------------- conv2: M=co2(512), N=128 (2 t x 8x8), K=27*512, K-split 4, 3-pass, swizzled -------------
__global__ __launch_bounds__(256, 2) void conv2_mfma(
        const _Float16* __restrict__ xh, const _Float16* __restrict__ xl,
        const _Float16* __restrict__ wh, const _Float16* __restrict__ wl,
        float* __restrict__ x2p) {
    __shared__ __align__(16) _Float16 Ah[128 * 32];
    __shared__ __align__(16) _Float16 Al[128 * 32];
    __shared__ __align__(16) _Float16 Bh[128 * 32];
    __shared__ __align__(16) _Float16 Bl[128 * 32];
    const int tid = threadIdx.x;
    const int co_blk = blockIdx.x;      // 0..3
    const int tp = blockIdx.y;          // 0..31  (t pair)
    const int ks = blockIdx.z;          // 0..3   (K split)
    const int wid = tid >> 6, lane = tid & 63;
    const int wm = wid & 1, wn = wid >> 1;
    const int sr = tid >> 2, sch = tid & 3;
    const int ml = lane & 15;
    const int ssel = (sr >> 1) & 3;
    const int sch2 = sch ^ ssel;
    const int kq = (((lane >> 4) ^ ((ml >> 1) & 3))) * 8;

    floatx4 zz = {0.f, 0.f, 0.f, 0.f};
    floatx4 acc[4][4];
#pragma unroll
    for (int i = 0; i < 4; ++i)
#pragma unroll
        for (int j = 0; j < 4; ++j) acc[i][j] = zz;

    const size_t wbo = (size_t)co_blk * 128 * 13824;

    for (int i = 0; i < 108; ++i) {
        const int kc = ks * 108 + i;
        const int tap = kc >> 4;
        const int ci0 = (kc & 15) << 5;
        const int kt = tap / 9;
        const int r9 = tap - kt * 9;
        const int kh = r9 / 3;
        const int kw = r9 - kh * 3;
        __syncthreads();
        {
            const size_t g = wbo + (size_t)sr * 13824 + tap * 512 + ci0 + sch2 * 8;
            gl_lds16(wh + g, &Ah[tid * 8]);
            gl_lds16(wh + g + (size_t)64 * 13824, &Ah[2048 + tid * 8]);
            gl_lds16(wl + g, &Al[tid * 8]);
            gl_lds16(wl + g + (size_t)64 * 13824, &Al[2048 + tid * 8]);
        }
        {
#pragma unroll
            for (int rb = 0; rb < 2; ++rb) {
                const int n = sr + rb * 64;
                const int tl = n >> 6, sp = n & 63;
                const int h = sp >> 3, w = sp & 7;
                const int it = tp * 2 + tl + kt - 1;
                const int ih = 2 * h + kh - 1, iw = 2 * w + kw - 1;
                uint4 vh = make_uint4(0u, 0u, 0u, 0u);
                uint4 vl = make_uint4(0u, 0u, 0u, 0u);
                if (((unsigned)it < 64u) && ((unsigned)ih < 16u) && ((unsigned)iw < 16u)) {
                    const size_t off = (((size_t)it * 16 + ih) * 16 + iw) * 512 + ci0 + sch * 8;
                    vh = *(const uint4*)(xh + off);
                    vl = *(const uint4*)(xl + off);
                }
                *(uint4*)&Bh[n * 32 + sch2 * 8] = vh;
                *(uint4*)&Bl[n * 32 + sch2 * 8] = vl;
            }
        }
        __syncthreads();
        half8 ah[4], alo[4], bh[4], blo[4];
#pragma unroll
        for (int mi = 0; mi < 4; ++mi) {
            ah[mi]  = *(const half8*)&Ah[(wm * 64 + mi * 16 + ml) * 32 + kq];
            alo[mi] = *(const half8*)&Al[(wm * 64 + mi * 16 + ml) * 32 + kq];
        }
#pragma unroll
        for (int ni = 0; ni < 4; ++ni) {
            bh[ni]  = *(const half8*)&Bh[(wn * 64 + ni * 16 + ml) * 32 + kq];
            blo[ni] = *(const half8*)&Bl[(wn * 64 + ni * 16 + ml) * 32 + kq];
        }
#pragma unroll
        for (int mi = 0; mi < 4; ++mi)
#pragma unroll
            for (int ni = 0; ni < 4; ++ni) {
                acc[mi][ni] = __builtin_amdgcn_mfma_f32_16x16x32_f16(ah[mi],  bh[ni],  acc[mi][ni], 0, 0, 0);
                acc[mi][ni] = __builtin_amdgcn_mfma_f32_16x16x32_f16(ah[mi],  blo[ni], acc[mi][ni], 0, 0, 0);
                acc[mi][ni] = __builtin_amdgcn_mfma_f32_16x16x32_f16(alo[mi], bh[ni],  acc[mi][ni], 0, 0, 0);
            }
    }

    // epilogue: fp32 partials, channel-last (ks, 4096 n, 512 co), float4 stores
    const int qr = (lane >> 4) * 4;
#pragma unroll
    for (int mi = 0; mi < 4; ++mi) {
        const int co = co_blk * 128 + wm * 64 + mi * 16 + qr;
#pragma unroll
        for (int ni = 0; ni < 4; ++ni) {
            const int n = wn * 64 + ni * 16 + ml;     // 0..127 within block
            const int ng = tp * 128 + n;              // global n = t*64 + sp
            float4 v;
            v.x = acc[mi][ni][0]; v.y = acc[mi][ni][1];
            v.z = acc[mi][ni][2]; v.w = acc[mi][ni][3];
            *(float4*)&x2p[((size_t)ks * 4096 + ng) * 512 + co] = v;
        }
    }
}

// ------------- feat: sum 4 K-split partials, unscale, max over 64 spatial, +bias -------------
__global__ void feat_reduce(const float* __restrict__ x2p,
                            const float* __restrict__ b2,
                            float* __restrict__ feat) {
    const int idx = blockIdx.x * 256 + threadIdx.x;   // 32768 = 64*512
    const int t = idx >> 9, c = idx & 511;
    float mx = -3.4e38f;
    for (int sp = 0; sp < 64; ++sp) {
        const size_t ng = (size_t)t * 64 + sp;
        float s = x2p[ng * 512 + c]
                + x2p[((size_t)4096 + ng) * 512 + c]
                + x2p[((size_t)8192 + ng) * 512 + c]
                + x2p[((size_t)12288 + ng) * 512 + c];
        mx = fmaxf(mx, s);
    }
    feat[(size_t)t * 512 + c] = mx * 0.015625f + b2[c];
}

// ------------- head: scores/deltas (32 x 64) = W(32x512) @ feat^T (fp32) -------------
__global__ void head_kernel(const float* __restrict__ feat,
                            const float* __restrict__ sw,
                            const float* __restrict__ sb,
                            const float* __restrict__ dw,
                            const float* __restrict__ db,
                            float* __restrict__ scoreL,
                            float* __restrict__ deltaL) {
    __shared__ float fr[512];
    __shared__ float partial[32][8];
    const int t = blockIdx.x, tid = threadIdx.x;
    fr[tid] = feat[(size_t)t * 512 + tid];
    fr[tid + 256] = feat[(size_t)t * 512 + 256 + tid];
    __syncthreads();
    const int o = tid & 31, part = tid >> 5;
    const float* wrow = (o < 16) ? (sw + (size_t)o * 512) : (dw + (size_t)(o - 16) * 512);
    float s = 0.f;
    const int j0 = part * 64;
#pragma unroll 16
    for (int j = 0; j < 64; ++j) s += wrow[j0 + j] * fr[j0 + j];
    partial[o][part] = s;
    __syncthreads();
    if (tid < 32) {
        float tot = 0.f;
#pragma unroll
        for (int p = 0; p < 8; ++p) tot += partial[tid][p];
        tot += (tid < 16) ? sb[tid] : db[tid - 16];
        if (tid < 16) scoreL[tid * 64 + t] = tot;
        else deltaL[(tid - 16) * 64 + t] = tot;
    }
}

// ------------- NMS + labels + losses (single block), fp32 output -------------
__global__ void nms_loss_kernel(const float* __restrict__ scoreL,
                                const float* __restrict__ deltaL,
                                const float* __restrict__ gt,
                                const int* __restrict__ video_len,
                                float* __restrict__ out) {
    __shared__ float bs[512], be[512], fgv[512], lp0s[512], lp1s[512], dcs[512], dls[512];
    __shared__ float gs[8], ge[8];
    __shared__ int lab[512], argg[512];
    __shared__ float redv[4];
    __shared__ int redi[4];
    __shared__ float brd[2];
    __shared__ float rsum[4][4];

    const int tid = threadIdx.x;
    if (tid < 8) { gs[tid] = gt[2 * tid]; ge[tid] = gt[2 * tid + 1]; }

    for (int n = tid; n < 512; n += 256) {
        const int a = n >> 6, tt = n & 63;
        const float s0 = scoreL[a * 64 + tt], s1 = scoreL[(8 + a) * 64 + tt];
        const float mm = fmaxf(s0, s1);
        const float lse = mm + logf(expf(s0 - mm) + expf(s1 - mm));
        const float l0 = s0 - lse, l1 = s1 - lse;
        const float dc = deltaL[a * 64 + tt], dl = deltaL[(8 + a) * 64 + tt];
        const float alen = 8.0f * (float)(1 << a);
        const float center = ((float)tt + 0.5f) * 8.0f;
        const float pc = center + dc * alen;
        const float dlc = fminf(fmaxf(dl, -10.0f), 10.0f);
        const float pl = alen * expf(dlc);
        float ps = pc - pl * 0.5f; ps = fminf(fmaxf(ps, 0.0f), 512.0f);
        float pe = pc + pl * 0.5f; pe = fminf(fmaxf(pe, 0.0f), 512.0f);
        bs[n] = ps; be[n] = pe;
        fgv[n] = ((pe - ps) >= 4.0f) ? expf(l1) : -1e9f;
        lp0s[n] = l0; lp1s[n] = l1; dcs[n] = dc; dls[n] = dl;
    }
    __syncthreads();

    for (int itn = 0; itn < 100; ++itn) {
        float v = fgv[tid]; int idx = tid;
        { const float v2 = fgv[tid + 256]; if (v2 > v) { v = v2; idx = tid + 256; } }
#pragma unroll
        for (int off = 32; off > 0; off >>= 1) {
            const float ov = __shfl_down(v, off);
            const int oi = __shfl_down(idx, off);
            if (ov > v || (ov == v && oi < idx)) { v = ov; idx = oi; }
        }
        if ((tid & 63) == 0) { redv[tid >> 6] = v; redi[tid >> 6] = idx; }
        __syncthreads();
        if (tid == 0) {
            float bv = redv[0]; int bi = redi[0];
            for (int w2 = 1; w2 < 4; ++w2) {
                if (redv[w2] > bv || (redv[w2] == bv && redi[w2] < bi)) { bv = redv[w2]; bi = redi[w2]; }
            }
            brd[0] = bv; brd[1] = __int_as_float(bi);
            const bool kept = bv > -5e8f;
            out[2 * itn] = kept ? bs[bi] : 0.0f;
            out[2 * itn + 1] = kept ? be[bi] : 0.0f;
            out[200 + itn] = kept ? bv : 0.0f;
        }
        __syncthreads();
        const int bi = __float_as_int(brd[1]);
        const float b0 = bs[bi], b1v = be[bi];
#pragma unroll
        for (int rr = 0; rr < 2; ++rr) {
            const int n = tid + rr * 256;
            const float inter = fmaxf(fminf(b1v, be[n]) - fmaxf(b0, bs[n]), 0.0f);
            const float uni = (b1v - b0) + (be[n] - bs[n]) - inter;
            const float iou = inter / fmaxf(uni, 1e-6f);
            if (iou > 0.7f || n == bi) fgv[n] = -1e9f;
        }
        __syncthreads();
    }

    // anchor labels vs GT
    for (int n = tid; n < 512; n += 256) {
        const int a = n >> 6, tt = n & 63;
        const float alen = 8.0f * (float)(1 << a);
        const float center = ((float)tt + 0.5f) * 8.0f;
        const float as_ = center - alen * 0.5f, ae_ = center + alen * 0.5f;
        float mx = -1.0f; int ag = 0;
        for (int g = 0; g < 8; ++g) {
            const float inter = fmaxf(fminf(ae_, ge[g]) - fmaxf(as_, gs[g]), 0.0f);
            const float uni = (ae_ - as_) + (ge[g] - gs[g]) - inter;
            const float iou = inter / fmaxf(uni, 1e-6f);
            if (iou > mx) { mx = iou; ag = g; }
        }
        int l = (mx < 0.3f) ? 0 : -1;
        if (mx >= 0.7f) l = 1;
        lab[n] = l; argg[n] = ag;
    }
    __syncthreads();

    // best anchor per GT -> force label 1 (first-max tie like jnp.argmax)
    for (int g = 0; g < 8; ++g) {
        float v = -1.0f; int idx = 0;
#pragma unroll
        for (int rr = 0; rr < 2; ++rr) {
            const int n = tid + rr * 256;
            const int a = n >> 6, tt = n & 63;
            const float alen = 8.0f * (float)(1 << a);
            const float center = ((float)tt + 0.5f) * 8.0f;
            const float as_ = center - alen * 0.5f, ae_ = center + alen * 0.5f;
            const float inter = fmaxf(fminf(ae_, ge[g]) - fmaxf(as_, gs[g]), 0.0f);
            const float uni = (ae_ - as_) + (ge[g] - gs[g]) - inter;
            const float iou = inter / fmaxf(uni, 1e-6f);
            if (iou > v || (iou == v && n < idx)) { v = iou; idx = n; }
        }
#pragma unroll
        for (int off = 32; off > 0; off >>= 1) {
            const float ov = __shfl_down(v, off);
            const int oi = __shfl_down(idx, off);
            if (ov > v || (ov == v && oi < idx)) { v = ov; idx = oi; }
        }
        if ((tid & 63) == 0) { redv[tid >> 6] = v; redi[tid >> 6] = idx; }
        __syncthreads();
        if (tid == 0) {
            float bv = redv[0]; int bi = redi[0];
            for (int w2 = 1; w2 < 4; ++w2) {
                if (redv[w2] > bv || (redv[w2] == bv && redi[w2] < bi)) { bv = redv[w2]; bi = redi[w2]; }
            }
            lab[bi] = 1;
        }
        __syncthreads();
    }

    // losses
    float nll_s = 0.f, msk_s = 0.f, reg_s = 0.f, pos_s = 0.f;
    const float vl = (float)video_len[0];
    for (int n = tid; n < 512; n += 256) {
        const int a = n >> 6, tt = n & 63;
        const float alen = 8.0f * (float)(1 << a);
        const float center = ((float)tt + 0.5f) * 8.0f;
        const float as_ = center - alen * 0.5f, ae_ = center + alen * 0.5f;
        int l = lab[n];
        if (!((as_ >= 0.0f) && (ae_ <= vl))) l = -1;
        if (l >= 0) {
            msk_s += 1.0f;
            nll_s -= (l == 1) ? lp1s[n] : lp0s[n];
            if (l == 1) {
                pos_s += 1.0f;
                const int g = argg[n];
                const float gc = (gs[g] + ge[g]) * 0.5f;
                const float gl = fmaxf(ge[g] - gs[g], 1e-6f);
                const float r0 = (gc - center) / alen;
                const float r1 = logf(gl / alen);
                const float d0 = dcs[n] - r0, d1 = dls[n] - r1;
                float s = (fabsf(d0) < 1.0f) ? (0.5f * d0 * d0) : (fabsf(d0) - 0.5f);
                s += (fabsf(d1) < 1.0f) ? (0.5f * d1 * d1) : (fabsf(d1) - 0.5f);
                reg_s += s;
            }
        }
    }
    float sums[4] = {nll_s, msk_s, reg_s, pos_s};
#pragma unroll
    for (int j = 0; j < 4; ++j) {
        float v = sums[j];
#pragma unroll
        for (int off = 32; off > 0; off >>= 1) v += __shfl_down(v, off);
        if ((tid & 63) == 0) rsum[tid >> 6][j] = v;
    }
    __syncthreads();
    if (tid == 0) {
        float tot[4];
#pragma unroll
        for (int j = 0; j < 4; ++j) tot[j] = rsum[0][j] + rsum[1][j] + rsum[2][j] + rsum[3][j];
        out[300] = tot[0] / fmaxf(tot[1], 1.0f);
        out[301] = tot[2] / fmaxf(tot[3], 1.0f);
    }
}

extern "C" void kernel_launch(void* const* d_in, const int* in_sizes, int n_in,
                              void* d_out, int out_size, void* d_ws, size_t ws_size,
                              hipStream_t stream) {
    const float* base_feat = (const float*)d_in[0];
    const float* gt        = (const float*)d_in[1];
    const int*   video_len = (const int*)d_in[2];
    const float* w1        = (const float*)d_in[3];
    const float* b1        = (const float*)d_in[4];
    const float* w2        = (const float*)d_in[5];
    const float* b2        = (const float*)d_in[6];
    const float* sw        = (const float*)d_in[7];
    const float* sb        = (const float*)d_in[8];
    const float* dw        = (const float*)d_in[9];
    const float* db        = (const float*)d_in[10];

    char* ws = (char*)d_ws;
    _Float16* w1h = (_Float16*)ws;  ws += (size_t)512 * 6912 * 2;       // 7,077,888
    _Float16* w1l = (_Float16*)ws;  ws += (size_t)512 * 6912 * 2;
    _Float16* w2h = (_Float16*)ws;  ws += (size_t)512 * 13824 * 2;      // 14,155,776
    _Float16* w2l = (_Float16*)ws;  ws += (size_t)512 * 13824 * 2;
    _Float16* inh = (_Float16*)ws;  ws += (size_t)65536 * 256 * 2;      // 33,554,432
    _Float16* inl = (_Float16*)ws;  ws += (size_t)65536 * 256 * 2;
    _Float16* x1h = (_Float16*)ws;  ws += (size_t)64 * 16 * 16 * 512 * 2;
    _Float16* x1l = (_Float16*)ws;  ws += (size_t)64 * 16 * 16 * 512 * 2;
    float* feat   = (float*)ws;     ws += (size_t)64 * 512 * 4;
    float* scoreL = (float*)ws;     ws += (size_t)16 * 64 * 4;
    float* deltaL = (float*)ws;     ws += (size_t)16 * 64 * 4;
    // x2p (4, 4096, 512) fp32 = 33.5 MB reuses the inh region (consumed by conv1)
    float* x2p = (float*)inh;

    wt_split<<<512, 256, 0, stream>>>(w1, w1h, w1l, 256);
    wt_split<<<512, 256, 0, stream>>>(w2, w2h, w2l, 512);
    in_split<<<dim3(4, 2048), 64, 0, stream>>>(base_feat, inh, inl);
    conv1_mfma<<<dim3(4, 64, 2), 256, 0, stream>>>(inh, inl, w1h, w1l, b1, x1h, x1l);
    conv2_mfma<<<dim3(4, 32, 4), 256, 0, stream>>>(x1h, x1l, w2h, w2l, x2p);
    feat_reduce<<<128, 256, 0, stream>>>(x2p, b2, feat);
    head_kernel<<<64, 256, 0, stream>>>(feat, sw, sb, dw, db, scoreL, deltaL);
    nms_loss_kernel<<<1, 256, 0, stream>>>(scoreL, deltaL, gt, video_len,
                                           (float*)d_out);
}

// Round 4
// 834.110 us; speedup vs baseline: 1.1820x; 1.1521x over previous
//
#include <hip/hip_runtime.h>

typedef __attribute__((ext_vector_type(8))) _Float16 half8;
typedef __attribute__((ext_vector_type(4))) _Float16 half4;
typedef __attribute__((ext_vector_type(4))) float floatx4;

#define DI __device__ __forceinline__

DI void gl_lds16(const void* g, void* l) {
    __builtin_amdgcn_global_load_lds(
        (__attribute__((address_space(1))) void*)(g),
        (__attribute__((address_space(3))) void*)(l), 16, 0, 0);
}

// ------------- weight split (both convs): (CO, CI, 27) fp32 -> (CO, 27, CI) f16 hi/lo, x64 scale -------------
__global__ void wt_split_both(const float* __restrict__ w1, _Float16* __restrict__ w1h,
                              _Float16* __restrict__ w1l, const float* __restrict__ w2,
                              _Float16* __restrict__ w2h, _Float16* __restrict__ w2l) {
    const int b = blockIdx.x;             // 0..1023
    const float* src;
    _Float16 *dh, *dl;
    int CI;
    if (b < 512) {
        CI = 256; src = w1 + (size_t)b * CI * 27;
        dh = w1h + (size_t)b * CI * 27; dl = w1l + (size_t)b * CI * 27;
    } else {
        CI = 512; src = w2 + (size_t)(b - 512) * CI * 27;
        dh = w2h + (size_t)(b - 512) * CI * 27; dl = w2l + (size_t)(b - 512) * CI * 27;
    }
    const int K = CI * 27;
    for (int idx = threadIdx.x; idx < K; idx += blockDim.x) {
        const int ci = idx / 27;
        const int tap = idx - ci * 27;
        const float x = src[idx] * 64.0f;          // scale lo-parts out of fp16 subnormals
        const _Float16 h = (_Float16)x;
        dh[tap * CI + ci] = h;
        dl[tap * CI + ci] = (_Float16)(x - (float)h);
    }
}

// ------------- input split+transpose: (256, 65536) fp32 -> (65536, 256) f16 hi/lo -------------
__global__ void in_split(const float* __restrict__ in, _Float16* __restrict__ oh,
                         _Float16* __restrict__ ol) {
    const int lane = threadIdx.x;                  // 64
    const int ci = blockIdx.x * 64 + lane;         // 0..255
    const int s0 = blockIdx.y * 32;                // 0..65535
    const float* src = in + (size_t)ci * 65536 + s0;
    float v[32];
#pragma unroll
    for (int q = 0; q < 8; ++q) *(float4*)(v + q * 4) = *(const float4*)(src + q * 4);
    const int cdst = blockIdx.x * 64 + lane;
#pragma unroll
    for (int j = 0; j < 32; ++j) {
        const _Float16 h = (_Float16)v[j];
        oh[(size_t)(s0 + j) * 256 + cdst] = h;
        ol[(size_t)(s0 + j) * 256 + cdst] = (_Float16)(v[j] - (float)h);
    }
}

// ------------- conv1: M=co(512), N=(t,h,w), K64/iter, ci-outer tap-inner, 3-pass hi/lo -------------
__global__ __launch_bounds__(256, 2) void conv1_mfma(
        const _Float16* __restrict__ xh, const _Float16* __restrict__ xl,
        const _Float16* __restrict__ wh, const _Float16* __restrict__ wl,
        const float* __restrict__ b1,
        _Float16* __restrict__ yh, _Float16* __restrict__ yl) {
    __shared__ __align__(16) _Float16 Ah[128 * 64];
    __shared__ __align__(16) _Float16 Al[128 * 64];
    __shared__ __align__(16) _Float16 Bh[128 * 64];
    __shared__ __align__(16) _Float16 Bl[128 * 64];
    const int tid = threadIdx.x;
    const int co_blk = blockIdx.x;      // 0..3
    const int t = blockIdx.y;           // 0..63
    const int h0 = blockIdx.z * 8;      // 0 or 8
    const int wid = tid >> 6, lane = tid & 63;
    const int wm = wid & 1, wn = wid >> 1;
    const int ml = lane & 15, ql = lane >> 4;
    // A-stage lane constants (gl_lds16 hw dest = wavebase + lane*16B)
    const int arow = lane >> 3;               // 0..7 row within 8-row issue
    const int achk = (lane & 7) ^ arow;       // logical 16B chunk to fetch (swizzle)
    const int aslot = lane & 7;
    // B-stage constants
    const int brow = tid >> 1;                // 0..127 (n row)
    const int bsel = (tid & 1) * 4;           // logical chunk base 0/4
    const int br7 = brow & 7;
    const int bh_ = h0 + (brow >> 4), bw_ = brow & 15;
    // frag read offsets (logical chunk 4u+ql stored at slot^(row&7), row&7==ml&7)
    const int cs0 = (ql ^ (ml & 7)) * 8;
    const int cs1 = ((4 + ql) ^ (ml & 7)) * 8;

    floatx4 zz = {0.f, 0.f, 0.f, 0.f};
    floatx4 acc[4][4];
#pragma unroll
    for (int i = 0; i < 4; ++i)
#pragma unroll
        for (int j = 0; j < 4; ++j) acc[i][j] = zz;

    const size_t wbo = (size_t)co_blk * 128 * 6912;

    int tap = 0, ci0 = 0;
    for (int i = 0; i < 108; ++i) {
        const int kt = tap / 9;
        const int r9 = tap - kt * 9;
        const int kh = r9 / 3;
        const int kw = r9 - kh * 3;
        const int it = t + kt - 1;
        const bool tok = ((unsigned)it < 64u);
        __syncthreads();
        {   // A stage: 128 rows x 64 k (hi+lo), 4 issues/wave/tensor
            const size_t gb = wbo + (size_t)tap * 256 + ci0 + achk * 8;
#pragma unroll
            for (int q = 0; q < 4; ++q) {
                const int r = wid * 32 + q * 8 + arow;
                const size_t g = gb + (size_t)r * 6912;
                gl_lds16(wh + g, &Ah[r * 64 + aslot * 8]);
                gl_lds16(wl + g, &Al[r * 64 + aslot * 8]);
            }
        }
        {   // B stage: im2col gather, 64B/thread/tensor, swizzled ds_write_b128
            const int ih = 2 * bh_ + kh - 1, iw = 2 * bw_ + kw - 1;
            const bool ok = tok && ((unsigned)ih < 32u) && ((unsigned)iw < 32u);
            uint4 vh4[4], vl4[4];
#pragma unroll
            for (int j2 = 0; j2 < 4; ++j2) {
                vh4[j2] = make_uint4(0u, 0u, 0u, 0u);
                vl4[j2] = make_uint4(0u, 0u, 0u, 0u);
            }
            if (ok) {
                const size_t src = (((size_t)it * 32 + ih) * 32 + iw) * 256 + ci0 + bsel * 8;
#pragma unroll
                for (int j2 = 0; j2 < 4; ++j2) {
                    vh4[j2] = *(const uint4*)(xh + src + j2 * 8);
                    vl4[j2] = *(const uint4*)(xl + src + j2 * 8);
                }
            }
#pragma unroll
            for (int j2 = 0; j2 < 4; ++j2) {
                const int slot = (bsel + j2) ^ br7;
                *(uint4*)&Bh[brow * 64 + slot * 8] = vh4[j2];
                *(uint4*)&Bl[brow * 64 + slot * 8] = vl4[j2];
            }
        }
        __syncthreads();
#pragma unroll
        for (int u = 0; u < 2; ++u) {
            const int cs = (u == 0) ? cs0 : cs1;
            half8 ah[4], alo[4], bh8[4], blo[4];
#pragma unroll
            for (int mi = 0; mi < 4; ++mi) {
                ah[mi]  = *(const half8*)&Ah[(wm * 64 + mi * 16 + ml) * 64 + cs];
                alo[mi] = *(const half8*)&Al[(wm * 64 + mi * 16 + ml) * 64 + cs];
            }
#pragma unroll
            for (int ni = 0; ni < 4; ++ni) {
                bh8[ni] = *(const half8*)&Bh[(wn * 64 + ni * 16 + ml) * 64 + cs];
                blo[ni] = *(const half8*)&Bl[(wn * 64 + ni * 16 + ml) * 64 + cs];
            }
#pragma unroll
            for (int mi = 0; mi < 4; ++mi)
#pragma unroll
                for (int ni = 0; ni < 4; ++ni) {
                    acc[mi][ni] = __builtin_amdgcn_mfma_f32_16x16x32_f16(ah[mi],  bh8[ni], acc[mi][ni], 0, 0, 0);
                    acc[mi][ni] = __builtin_amdgcn_mfma_f32_16x16x32_f16(ah[mi],  blo[ni], acc[mi][ni], 0, 0, 0);
                    acc[mi][ni] = __builtin_amdgcn_mfma_f32_16x16x32_f16(alo[mi], bh8[ni], acc[mi][ni], 0, 0, 0);
                }
        }
        if (++tap == 27) { tap = 0; ci0 += 64; }
    }

    // epilogue: unscale, +bias, split fp32 into f16 hi/lo, store channel-last
    const int qr = ql * 4;
#pragma unroll
    for (int mi = 0; mi < 4; ++mi) {
        const int co = co_blk * 128 + wm * 64 + mi * 16 + qr;
#pragma unroll
        for (int ni = 0; ni < 4; ++ni) {
            const int n = wn * 64 + ni * 16 + ml;
            const int h = h0 + (n >> 4), w = n & 15;
            const size_t base = (((size_t)t * 16 + h) * 16 + w) * 512 + co;
            half4 hv, lv;
#pragma unroll
            for (int r = 0; r < 4; ++r) {
                const float v = acc[mi][ni][r] * 0.015625f + b1[co + r];
                const _Float16 hb = (_Float16)v;
                hv[r] = hb;
                lv[r] = (_Float16)(v - (float)hb);
            }
            *(half4*)(yh + base) = hv;
            *(half4*)(yl + base) = lv;
        }
    }
}

// ------------- conv2: M=co2(512), N=128 (2t x 8x8), K64/iter, ci-outer tap-inner, K-split 4 -------------
__global__ __launch_bounds__(256, 2) void conv2_mfma(
        const _Float16* __restrict__ xh, const _Float16* __restrict__ xl,
        const _Float16* __restrict__ wh, const _Float16* __restrict__ wl,
        float* __restrict__ x2p) {
    __shared__ __align__(16) _Float16 Ah[128 * 64];
    __shared__ __align__(16) _Float16 Al[128 * 64];
    __shared__ __align__(16) _Float16 Bh[128 * 64];
    __shared__ __align__(16) _Float16 Bl[128 * 64];
    const int tid = threadIdx.x;
    const int co_blk = blockIdx.x;      // 0..3
    const int tp = blockIdx.y;          // 0..31
    const int ks = blockIdx.z;          // 0..3
    const int wid = tid >> 6, lane = tid & 63;
    const int wm = wid & 1, wn = wid >> 1;
    const int ml = lane & 15, ql = lane >> 4;
    const int arow = lane >> 3;
    const int achk = (lane & 7) ^ arow;
    const int aslot = lane & 7;
    const int brow = tid >> 1;
    const int bsel = (tid & 1) * 4;
    const int br7 = brow & 7;
    const int btl = brow >> 6, bsp = brow & 63;
    const int bh_ = bsp >> 3, bw_ = bsp & 7;
    const int cs0 = (ql ^ (ml & 7)) * 8;
    const int cs1 = ((4 + ql) ^ (ml & 7)) * 8;

    floatx4 zz = {0.f, 0.f, 0.f, 0.f};
    floatx4 acc[4][4];
#pragma unroll
    for (int i = 0; i < 4; ++i)
#pragma unroll
        for (int j = 0; j < 4; ++j) acc[i][j] = zz;

    const size_t wbo = (size_t)co_blk * 128 * 13824;

    int tap = 0, ci0 = ks * 128;        // covers ci64 blocks {2ks, 2ks+1}
    for (int i = 0; i < 54; ++i) {
        const int kt = tap / 9;
        const int r9 = tap - kt * 9;
        const int kh = r9 / 3;
        const int kw = r9 - kh * 3;
        __syncthreads();
        {
            const size_t gb = wbo + (size_t)tap * 512 + ci0 + achk * 8;
#pragma unroll
            for (int q = 0; q < 4; ++q) {
                const int r = wid * 32 + q * 8 + arow;
                const size_t g = gb + (size_t)r * 13824;
                gl_lds16(wh + g, &Ah[r * 64 + aslot * 8]);
                gl_lds16(wl + g, &Al[r * 64 + aslot * 8]);
            }
        }
        {
            const int it = tp * 2 + btl + kt - 1;
            const int ih = 2 * bh_ + kh - 1, iw = 2 * bw_ + kw - 1;
            const bool ok = ((unsigned)it < 64u) && ((unsigned)ih < 16u) && ((unsigned)iw < 16u);
            uint4 vh4[4], vl4[4];
#pragma unroll
            for (int j2 = 0; j2 < 4; ++j2) {
                vh4[j2] = make_uint4(0u, 0u, 0u, 0u);
                vl4[j2] = make_uint4(0u, 0u, 0u, 0u);
            }
            if (ok) {
                const size_t src = (((size_t)it * 16 + ih) * 16 + iw) * 512 + ci0 + bsel * 8;
#pragma unroll
                for (int j2 = 0; j2 < 4; ++j2) {
                    vh4[j2] = *(const uint4*)(xh + src + j2 * 8);
                    vl4[j2] = *(const uint4*)(xl + src + j2 * 8);
                }
            }
#pragma unroll
            for (int j2 = 0; j2 < 4; ++j2) {
                const int slot = (bsel + j2) ^ br7;
                *(uint4*)&Bh[brow * 64 + slot * 8] = vh4[j2];
                *(uint4*)&Bl[brow * 64 + slot * 8] = vl4[j2];
            }
        }
        __syncthreads();
#pragma unroll
        for (int u = 0; u < 2; ++u) {
            const int cs = (u == 0) ? cs0 : cs1;
            half8 ah[4], alo[4], bh8[4], blo[4];
#pragma unroll
            for (int mi = 0; mi < 4; ++mi) {
                ah[mi]  = *(const half8*)&Ah[(wm * 64 + mi * 16 + ml) * 64 + cs];
                alo[mi] = *(const half8*)&Al[(wm * 64 + mi * 16 + ml) * 64 + cs];
            }
#pragma unroll
            for (int ni = 0; ni < 4; ++ni) {
                bh8[ni] = *(const half8*)&Bh[(wn * 64 + ni * 16 + ml) * 64 + cs];
                blo[ni] = *(const half8*)&Bl[(wn * 64 + ni * 16 + ml) * 64 + cs];
            }
#pragma unroll
            for (int mi = 0; mi < 4; ++mi)
#pragma unroll
                for (int ni = 0; ni < 4; ++ni) {
                    acc[mi][ni] = __builtin_amdgcn_mfma_f32_16x16x32_f16(ah[mi],  bh8[ni], acc[mi][ni], 0, 0, 0);
                    acc[mi][ni] = __builtin_amdgcn_mfma_f32_16x16x32_f16(ah[mi],  blo[ni], acc[mi][ni], 0, 0, 0);
                    acc[mi][ni] = __builtin_amdgcn_mfma_f32_16x16x32_f16(alo[mi], bh8[ni], acc[mi][ni], 0, 0, 0);
                }
        }
        if (++tap == 27) { tap = 0; ci0 += 64; }
    }

    // epilogue: fp32 partials, channel-last (ks, 4096 n, 512 co), float4 stores
    const int qr = ql * 4;
#pragma unroll
    for (int mi = 0; mi < 4; ++mi) {
        const int co = co_blk * 128 + wm * 64 + mi * 16 + qr;
#pragma unroll
        for (int ni = 0; ni < 4; ++ni) {
            const int n = wn * 64 + ni * 16 + ml;
            const int ng = tp * 128 + n;
            float4 v;
            v.x = acc[mi][ni][0]; v.y = acc[mi][ni][1];
            v.z = acc[mi][ni][2]; v.w = acc[mi][ni][3];
            *(float4*)&x2p[((size_t)ks * 4096 + ng) * 512 + co] = v;
        }
    }
}

// ------------- feat: sum 4 K-split partials, unscale, max over 64 spatial, +bias -------------
__global__ void feat_reduce(const float* __restrict__ x2p,
                            const float* __restrict__ b2,
                            float* __restrict__ feat) {
    const int idx = blockIdx.x * 256 + threadIdx.x;   // 32768 = 64*512
    const int t = idx >> 9, c = idx & 511;
    float mx = -3.4e38f;
    for (int sp = 0; sp < 64; ++sp) {
        const size_t ng = (size_t)t * 64 + sp;
        float s = x2p[ng * 512 + c]
                + x2p[((size_t)4096 + ng) * 512 + c]
                + x2p[((size_t)8192 + ng) * 512 + c]
                + x2p[((size_t)12288 + ng) * 512 + c];
        mx = fmaxf(mx, s);
    }
    feat[(size_t)t * 512 + c] = mx * 0.015625f + b2[c];
}

// ------------- head: scores/deltas (32 x 64) = W(32x512) @ feat^T (fp32) -------------
__global__ void head_kernel(const float* __restrict__ feat,
                            const float* __restrict__ sw,
                            const float* __restrict__ sb,
                            const float* __restrict__ dw,
                            const float* __restrict__ db,
                            float* __restrict__ scoreL,
                            float* __restrict__ deltaL) {
    __shared__ float fr[512];
    __shared__ float partial[32][8];
    const int t = blockIdx.x, tid = threadIdx.x;
    fr[tid] = feat[(size_t)t * 512 + tid];
    fr[tid + 256] = feat[(size_t)t * 512 + 256 + tid];
    __syncthreads();
    const int o = tid & 31, part = tid >> 5;
    const float* wrow = (o < 16) ? (sw + (size_t)o * 512) : (dw + (size_t)(o - 16) * 512);
    float s = 0.f;
    const int j0 = part * 64;
#pragma unroll 16
    for (int j = 0; j < 64; ++j) s += wrow[j0 + j] * fr[j0 + j];
    partial[o][part] = s;
    __syncthreads();
    if (tid < 32) {
        float tot = 0.f;
#pragma unroll
        for (int p = 0; p < 8; ++p) tot += partial[tid][p];
        tot += (tid < 16) ? sb[tid] : db[tid - 16];
        if (tid < 16) scoreL[tid * 64 + t] = tot;
        else deltaL[(tid - 16) * 64 + t] = tot;
    }
}

// ------------- NMS + labels + losses: SINGLE WAVE (64 lanes), no barriers -------------
__global__ void nms_loss_kernel(const float* __restrict__ scoreL,
                                const float* __restrict__ deltaL,
                                const float* __restrict__ gt,
                                const int* __restrict__ video_len,
                                float* __restrict__ out) {
    const int lane = threadIdx.x & 63;
    float gsv[8], gev[8];
#pragma unroll
    for (int g = 0; g < 8; ++g) { gsv[g] = gt[2 * g]; gev[g] = gt[2 * g + 1]; }
    const float center = ((float)lane + 0.5f) * 8.0f;
    // lane owns anchors n = lane + 64*j  (a=j scale, tt=lane)
    float psv[8], pev[8], fg[8], l0v[8], l1v[8], dcv[8], dlv[8];
#pragma unroll
    for (int j = 0; j < 8; ++j) {
        const float s0 = scoreL[j * 64 + lane], s1 = scoreL[(8 + j) * 64 + lane];
        const float mm = fmaxf(s0, s1);
        const float lse = mm + logf(expf(s0 - mm) + expf(s1 - mm));
        l0v[j] = s0 - lse; l1v[j] = s1 - lse;
        const float dc = deltaL[j * 64 + lane], dl = deltaL[(8 + j) * 64 + lane];
        dcv[j] = dc; dlv[j] = dl;
        const float alen = 8.0f * (float)(1 << j);
        const float pc = center + dc * alen;
        const float pl = alen * expf(fminf(fmaxf(dl, -10.0f), 10.0f));
        const float ps = fminf(fmaxf(pc - pl * 0.5f, 0.0f), 512.0f);
        const float pe = fminf(fmaxf(pc + pl * 0.5f, 0.0f), 512.0f);
        psv[j] = ps; pev[j] = pe;
        fg[j] = ((pe - ps) >= 4.0f) ? expf(l1v[j]) : -1e9f;
    }
    for (int itn = 0; itn < 100; ++itn) {
        float v = fg[0]; int idx = lane;
#pragma unroll
        for (int j = 1; j < 8; ++j) if (fg[j] > v) { v = fg[j]; idx = lane + 64 * j; }
#pragma unroll
        for (int off = 32; off > 0; off >>= 1) {
            const float ov = __shfl_down(v, off);
            const int oi = __shfl_down(idx, off);
            if (ov > v || (ov == v && oi < idx)) { v = ov; idx = oi; }
        }
        v = __shfl(v, 0); idx = __shfl(idx, 0);
        const int wj = idx >> 6, wl = idx & 63;
        float bw0 = 0.f, bw1 = 0.f;
#pragma unroll
        for (int j = 0; j < 8; ++j) if (j == wj) { bw0 = psv[j]; bw1 = pev[j]; }
        const float b0 = __shfl(bw0, wl);
        const float b1 = __shfl(bw1, wl);
        if (lane == 0) {
            const bool kept = v > -5e8f;
            out[2 * itn] = kept ? b0 : 0.0f;
            out[2 * itn + 1] = kept ? b1 : 0.0f;
            out[200 + itn] = kept ? v : 0.0f;
        }
#pragma unroll
        for (int j = 0; j < 8; ++j) {
            const int n = lane + 64 * j;
            const float inter = fmaxf(fminf(b1, pev[j]) - fmaxf(b0, psv[j]), 0.0f);
            const float uni = (b1 - b0) + (pev[j] - psv[j]) - inter;
            const float iou = inter / fmaxf(uni, 1e-6f);
            if (iou > 0.7f || n == idx) fg[j] = -1e9f;
        }
    }
    // anchor labels vs GT
    int labv[8], aggv[8];
#pragma unroll
    for (int j = 0; j < 8; ++j) {
        const float alen = 8.0f * (float)(1 << j);
        const float as_ = center - alen * 0.5f, ae_ = center + alen * 0.5f;
        float mx = -1.0f; int ag = 0;
#pragma unroll
        for (int g = 0; g < 8; ++g) {
            const float inter = fmaxf(fminf(ae_, gev[g]) - fmaxf(as_, gsv[g]), 0.0f);
            const float uni = (ae_ - as_) + (gev[g] - gsv[g]) - inter;
            const float iou = inter / fmaxf(uni, 1e-6f);
            if (iou > mx) { mx = iou; ag = g; }
        }
        labv[j] = (mx < 0.3f) ? 0 : ((mx >= 0.7f) ? 1 : -1);
        aggv[j] = ag;
    }
    // best anchor per GT -> force label 1 (first-max tie like jnp.argmax)
    for (int g = 0; g < 8; ++g) {
        float v = -1.0f; int idx = 0;
#pragma unroll
        for (int j = 0; j < 8; ++j) {
            const int n = lane + 64 * j;
            const float alen = 8.0f * (float)(1 << j);
            const float as_ = center - alen * 0.5f, ae_ = center + alen * 0.5f;
            const float inter = fmaxf(fminf(ae_, gev[g]) - fmaxf(as_, gsv[g]), 0.0f);
            const float uni = (ae_ - as_) + (gev[g] - gsv[g]) - inter;
            const float iou = inter / fmaxf(uni, 1e-6f);
            if (iou > v || (iou == v && n < idx)) { v = iou; idx = n; }
        }
#pragma unroll
        for (int off = 32; off > 0; off >>= 1) {
            const float ov = __shfl_down(v, off);
            const int oi = __shfl_down(idx, off);
            if (ov > v || (ov == v && oi < idx)) { v = ov; idx = oi; }
        }
        idx = __shfl(idx, 0);
#pragma unroll
        for (int j = 0; j < 8; ++j)
            if (lane == (idx & 63) && j == (idx >> 6)) labv[j] = 1;
    }
    // losses
    const float vl = (float)video_len[0];
    float nll_s = 0.f, msk_s = 0.f, reg_s = 0.f, pos_s = 0.f;
#pragma unroll
    for (int j = 0; j < 8; ++j) {
        const float alen = 8.0f * (float)(1 << j);
        const float as_ = center - alen * 0.5f, ae_ = center + alen * 0.5f;
        int l = labv[j];
        if (!((as_ >= 0.0f) && (ae_ <= vl))) l = -1;
        if (l >= 0) {
            msk_s += 1.0f;
            nll_s -= (l == 1) ? l1v[j] : l0v[j];
            if (l == 1) {
                pos_s += 1.0f;
                float gcv = 0.f, glv = 0.f;
#pragma unroll
                for (int g = 0; g < 8; ++g)
                    if (g == aggv[j]) {
                        gcv = (gsv[g] + gev[g]) * 0.5f;
                        glv = fmaxf(gev[g] - gsv[g], 1e-6f);
                    }
                const float r0 = (gcv - center) / alen;
                const float r1 = logf(glv / alen);
                const float d0 = dcv[j] - r0, d1 = dlv[j] - r1;
                float s = (fabsf(d0) < 1.0f) ? (0.5f * d0 * d0) : (fabsf(d0) - 0.5f);
                s += (fabsf(d1) < 1.0f) ? (0.5f * d1 * d1) : (fabsf(d1) - 0.5f);
                reg_s += s;
            }
        }
    }
    float sums[4] = {nll_s, msk_s, reg_s, pos_s};
#pragma unroll
    for (int k = 0; k < 4; ++k)
#pragma unroll
        for (int off = 32; off > 0; off >>= 1) sums[k] += __shfl_down(sums[k], off);
    if (lane == 0) {
        out[300] = sums[0] / fmaxf(sums[1], 1.0f);
        out[301] = sums[2] / fmaxf(sums[3], 1.0f);
    }
}

extern "C" void kernel_launch(void* const* d_in, const int* in_sizes, int n_in,
                              void* d_out, int out_size, void* d_ws, size_t ws_size,
                              hipStream_t stream) {
    const float* base_feat = (const float*)d_in[0];
    const float* gt        = (const float*)d_in[1];
    const int*   video_len = (const int*)d_in[2];
    const float* w1        = (const float*)d_in[3];
    const float* b1        = (const float*)d_in[4];
    const float* w2        = (const float*)d_in[5];
    const float* b2        = (const float*)d_in[6];
    const float* sw        = (const float*)d_in[7];
    const float* sb        = (const float*)d_in[8];
    const float* dw        = (const float*)d_in[9];
    const float* db        = (const float*)d_in[10];

    char* ws = (char*)d_ws;
    _Float16* w1h = (_Float16*)ws;  ws += (size_t)512 * 6912 * 2;
    _Float16* w1l = (_Float16*)ws;  ws += (size_t)512 * 6912 * 2;
    _Float16* w2h = (_Float16*)ws;  ws += (size_t)512 * 13824 * 2;
    _Float16* w2l = (_Float16*)ws;  ws += (size_t)512 * 13824 * 2;
    _Float16* inh = (_Float16*)ws;  ws += (size_t)65536 * 256 * 2;
    _Float16* inl = (_Float16*)ws;  ws += (size_t)65536 * 256 * 2;
    _Float16* x1h = (_Float16*)ws;  ws += (size_t)64 * 16 * 16 * 512 * 2;
    _Float16* x1l = (_Float16*)ws;  ws += (size_t)64 * 16 * 16 * 512 * 2;
    float* feat   = (float*)ws;     ws += (size_t)64 * 512 * 4;
    float* scoreL = (float*)ws;     ws += (size_t)16 * 64 * 4;
    float* deltaL = (float*)ws;     ws += (size_t)16 * 64 * 4;
    // x2p (4, 4096, 512) fp32 = 33.5 MB reuses the inh region (consumed by conv1)
    float* x2p = (float*)inh;

    wt_split_both<<<1024, 256, 0, stream>>>(w1, w1h, w1l, w2, w2h, w2l);
    in_split<<<dim3(4, 2048), 64, 0, stream>>>(base_feat, inh, inl);
    conv1_mfma<<<dim3(4, 64, 2), 256, 0, stream>>>(inh, inl, w1h, w1l, b1, x1h, x1l);
    conv2_mfma<<<dim3(4, 32, 4), 256, 0, stream>>>(x1h, x1l, w2h, w2l, x2p);
    feat_reduce<<<128, 256, 0, stream>>>(x2p, b2, feat);
    head_kernel<<<64, 256, 0, stream>>>(feat, sw, sb, dw, db, scoreL, deltaL);
    nms_loss_kernel<<<1, 64, 0, stream>>>(scoreL, deltaL, gt, video_len,
                                          (float*)d_out);
}